// Round 3
// baseline (877.962 us; speedup 1.0000x reference)
//
#include <hip/hip_runtime.h>

// GRU-like fused pointwise-conv cell on MI355X (gfx950).
// B=32, C=64, H=64, L=32768. fp32 in/out; split-bf16 (hi+lo) MFMA internally.
// Round 2 (resubmit): 32KB LDS (5 blocks/CU), cvt_pk staging, bias-in-acc,
// global hval prefetch hoisted above MFMA, shared B-frags, exp2/rcp epilogue.

typedef short s16x4 __attribute__((ext_vector_type(4)));
typedef short s16x8 __attribute__((ext_vector_type(8)));
typedef float f32x4 __attribute__((ext_vector_type(4)));
typedef unsigned u32x2 __attribute__((ext_vector_type(2)));

#define L_TOT 32768
#define LT 64          // l-points per workgroup

__device__ __forceinline__ short f2bf(float f) {
  union { float f; unsigned u; } v; v.f = f;
  unsigned r = v.u + 0x7fffu + ((v.u >> 16) & 1u);  // RNE
  return (short)(r >> 16);
}
__device__ __forceinline__ float bf2f(short s) {
  union { unsigned u; float f; } v; v.u = ((unsigned)(unsigned short)s) << 16;
  return v.f;
}
__device__ __forceinline__ unsigned cvt_pk_bf16(float a, float b) {
  unsigned r;
  asm("v_cvt_pk_bf16_f32 %0, %1, %2" : "=v"(r) : "v"(a), "v"(b));
  return r;
}
__device__ __forceinline__ float from_lo(unsigned p) {
  union { unsigned u; float f; } v; v.u = p << 16; return v.f;
}
__device__ __forceinline__ float from_hi(unsigned p) {
  union { unsigned u; float f; } v; v.u = p & 0xffff0000u; return v.f;
}
__device__ __forceinline__ float v_exp2(float x) {
  float r; asm("v_exp_f32 %0, %1" : "=v"(r) : "v"(x)); return r;
}
__device__ __forceinline__ float v_rcp(float x) {
  float r; asm("v_rcp_f32 %0, %1" : "=v"(r) : "v"(x)); return r;
}
__device__ __forceinline__ float fast_sigmoid(float x) {
  return v_rcp(1.0f + v_exp2(-1.4426950408889634f * x));
}
__device__ __forceinline__ float fast_tanh(float x) {
  return 1.0f - 2.0f * v_rcp(1.0f + v_exp2(2.8853900817779268f * x));
}

// Split W_r / W_u / W_h (each [64][128] fp32) into bf16 hi/lo arrays [192][128].
__global__ __launch_bounds__(256) void prep_weights(
    const float* __restrict__ Wr, const float* __restrict__ Wu,
    const float* __restrict__ Wh, short* __restrict__ whi,
    short* __restrict__ wlo) {
  int i = blockIdx.x * 256 + threadIdx.x;
  if (i >= 192 * 128) return;
  int r = i >> 7, c = i & 127;
  const float* src = (r < 64) ? Wr : ((r < 128) ? Wu : Wh);
  float w = src[((r & 63) << 7) | c];
  short hi = f2bf(w);
  whi[i] = hi;
  wlo[i] = f2bf(w - bf2f(hi));
}

// xt: [64 l][128 c] bf16, rows = 16 slots of 16B; swizzle spreads both the
// staging writes (4-way) and the fragment reads (balanced across banks).
__device__ __forceinline__ int xt_idx(int l, int c) {
  int slot = ((c >> 3) ^ (l & 15) ^ (l >> 4)) & 15;
  return l * 128 + slot * 8 + (c & 7);
}
// hr: [64 l][64 c] bf16, rows = 8 slots of 16B.
__device__ __forceinline__ int hr_idx(int l, int c) {
  int slot = ((c >> 3) ^ l) & 7;
  return l * 64 + slot * 8 + (c & 7);
}

#define MFMA(a, b, c) __builtin_amdgcn_mfma_f32_16x16x32_bf16(a, b, c, 0, 0, 0)

__global__ __launch_bounds__(256, 5) void gru_main(
    const float* __restrict__ xin, const float* __restrict__ hin,
    const short* __restrict__ whi, const short* __restrict__ wlo,
    const float* __restrict__ pbr, const float* __restrict__ pbu,
    const float* __restrict__ pbh, float* __restrict__ out) {
  __shared__ __align__(16) short smem[16384];   // 32 KiB total
  short* const xt_hi = smem;                    // 16 KiB [64][128]
  short* const xt_lo = smem + 8192;             // 16 KiB
  short* const hr_hi = smem;                    // 8 KiB, aliases xt_hi (dead)
  short* const hr_lo = smem + 4096;             // 8 KiB

  const int tid  = threadIdx.x;
  const int lane = tid & 63;
  const int wv   = tid >> 6;
  const int rA   = lane & 15;
  const int hi4  = (lane >> 4) << 2;   // 0,4,8,12 -> C/D reg-row base
  const int g8   = (lane >> 4) << 3;   // k-group offset
  const int l0   = blockIdx.x * LT;
  const int b    = blockIdx.y;
  const int ob   = wv * 16 + hi4;      // first output channel of this thread

  const float* xb = xin + (size_t)b * 64 * L_TOT + l0;
  const float* hb = hin + (size_t)b * 64 * L_TOT + l0;

  // Bias folded into accumulator init.
  f32x4 bR, bU, bN;
  #pragma unroll
  for (int r = 0; r < 4; ++r) {
    bR[r] = pbr[ob + r]; bU[r] = pbu[ob + r]; bN[r] = pbh[ob + r];
  }
  f32x4 accR[4], accU[4], accN[4];
  #pragma unroll
  for (int lt = 0; lt < 4; ++lt) { accR[lt] = bR; accU[lt] = bU; accN[lt] = bN; }

  // ---- Phase 1: stage X = [input; h] transposed [l][c], bf16 hi/lo split ----
  {
    const int l = lane;
    const float* src = (wv & 2) ? hb : xb;
    const int crel = (wv & 1) * 32;              // channel within source
    #pragma unroll
    for (int it = 0; it < 8; ++it) {
      const int cs = crel + it * 4;
      const int c0 = (wv & 2) * 32 + cs;         // global c: 0..127
      const float* p = src + (size_t)cs * L_TOT + l;
      float f0 = p[0];
      float f1 = p[L_TOT];
      float f2 = p[2 * L_TOT];
      float f3 = p[3 * L_TOT];
      unsigned h01 = cvt_pk_bf16(f0, f1);
      unsigned h23 = cvt_pk_bf16(f2, f3);
      unsigned q01 = cvt_pk_bf16(f0 - from_lo(h01), f1 - from_hi(h01));
      unsigned q23 = cvt_pk_bf16(f2 - from_lo(h23), f3 - from_hi(h23));
      const int idx = xt_idx(l, c0);
      *(u32x2*)&xt_hi[idx] = u32x2{h01, h23};
      *(u32x2*)&xt_lo[idx] = u32x2{q01, q23};
    }
  }

  // Prefetch h (exact fp32) from global for phase 4/6 — issued BEFORE the
  // MFMA block so HBM/L2 latency hides under the whole matmul phase.
  float hcache[4][4];
  #pragma unroll
  for (int lt = 0; lt < 4; ++lt)
    #pragma unroll
    for (int r = 0; r < 4; ++r)
      hcache[lt][r] = hb[(size_t)(ob + r) * L_TOT + lt * 16 + rA];

  __syncthreads();  // sync1: X staged

  auto ldA = [&](const short* wb, int row0, int kt) -> s16x8 {
    return *(const s16x8*)&wb[(row0 + rA) * 128 + kt * 32 + g8];
  };
  auto ldBx = [&](const short* sb, int lt, int kt) -> s16x8 {
    const int l = lt * 16 + rA;
    const int c = kt * 32 + g8;
    const int slot = ((c >> 3) ^ rA ^ lt) & 15;
    return *(const s16x8*)&sb[l * 128 + slot * 8];
  };
  auto ldBh = [&](const short* sb, int lt, int kt) -> s16x8 {
    const int l = lt * 16 + rA;
    const int c = kt * 32 + g8;
    const int slot = ((c >> 3) ^ (l & 7)) & 7;
    return *(const s16x8*)&sb[l * 64 + slot * 8];
  };

  // ---- Phase 2/3 merged: R,U over K=128; N over K=0..63 shares B-frags ----
  #pragma unroll
  for (int kt = 0; kt < 4; ++kt) {
    s16x8 arh = ldA(whi, wv * 16, kt);
    s16x8 arl = ldA(wlo, wv * 16, kt);
    s16x8 auh = ldA(whi, 64 + wv * 16, kt);
    s16x8 aul = ldA(wlo, 64 + wv * 16, kt);
    if (kt < 2) {
      s16x8 anh = ldA(whi, 128 + wv * 16, kt);
      s16x8 anl = ldA(wlo, 128 + wv * 16, kt);
      #pragma unroll
      for (int lt = 0; lt < 4; ++lt) {
        s16x8 bh = ldBx(xt_hi, lt, kt);
        s16x8 bl = ldBx(xt_lo, lt, kt);
        accR[lt] = MFMA(arh, bh, accR[lt]);
        accR[lt] = MFMA(arl, bh, accR[lt]);
        accR[lt] = MFMA(arh, bl, accR[lt]);
        accU[lt] = MFMA(auh, bh, accU[lt]);
        accU[lt] = MFMA(aul, bh, accU[lt]);
        accU[lt] = MFMA(auh, bl, accU[lt]);
        accN[lt] = MFMA(anh, bh, accN[lt]);
        accN[lt] = MFMA(anl, bh, accN[lt]);
        accN[lt] = MFMA(anh, bl, accN[lt]);
      }
    } else {
      #pragma unroll
      for (int lt = 0; lt < 4; ++lt) {
        s16x8 bh = ldBx(xt_hi, lt, kt);
        s16x8 bl = ldBx(xt_lo, lt, kt);
        accR[lt] = MFMA(arh, bh, accR[lt]);
        accR[lt] = MFMA(arl, bh, accR[lt]);
        accR[lt] = MFMA(arh, bl, accR[lt]);
        accU[lt] = MFMA(auh, bh, accU[lt]);
        accU[lt] = MFMA(aul, bh, accU[lt]);
        accU[lt] = MFMA(auh, bl, accU[lt]);
      }
    }
  }

  __syncthreads();  // sync2: all waves done READING xt (hr aliases xt_hi)

  // ---- Phase 4: r = sigmoid(accR); write h*r (hi/lo split, b64 packed) ----
  #pragma unroll
  for (int lt = 0; lt < 4; ++lt) {
    const int l = lt * 16 + rA;
    float g0 = fast_sigmoid(accR[lt][0]) * hcache[lt][0];
    float g1 = fast_sigmoid(accR[lt][1]) * hcache[lt][1];
    float g2 = fast_sigmoid(accR[lt][2]) * hcache[lt][2];
    float g3 = fast_sigmoid(accR[lt][3]) * hcache[lt][3];
    unsigned h01 = cvt_pk_bf16(g0, g1);
    unsigned h23 = cvt_pk_bf16(g2, g3);
    unsigned q01 = cvt_pk_bf16(g0 - from_lo(h01), g1 - from_hi(h01));
    unsigned q23 = cvt_pk_bf16(g2 - from_lo(h23), g3 - from_hi(h23));
    const int idx = hr_idx(l, ob);
    *(u32x2*)&hr_hi[idx] = u32x2{h01, h23};
    *(u32x2*)&hr_lo[idx] = u32x2{q01, q23};
  }
  __syncthreads();  // sync3: hr ready

  // ---- Phase 5: N += W_h[:, 64:128] @ (h*r) ----
  #pragma unroll
  for (int kt = 0; kt < 2; ++kt) {
    s16x8 anh = ldA(whi, 128 + wv * 16, 2 + kt);
    s16x8 anl = ldA(wlo, 128 + wv * 16, 2 + kt);
    #pragma unroll
    for (int lt = 0; lt < 4; ++lt) {
      s16x8 bh = ldBh(hr_hi, lt, kt);
      s16x8 bl = ldBh(hr_lo, lt, kt);
      accN[lt] = MFMA(anh, bh, accN[lt]);
      accN[lt] = MFMA(anl, bh, accN[lt]);
      accN[lt] = MFMA(anh, bl, accN[lt]);
    }
  }

  // ---- Phase 6: out = (1-u)*tanh(n) + u*h ----
  #pragma unroll
  for (int lt = 0; lt < 4; ++lt) {
    const int lg = l0 + lt * 16 + rA;
    #pragma unroll
    for (int r = 0; r < 4; ++r) {
      float u  = fast_sigmoid(accU[lt][r]);
      float nh = fast_tanh(accN[lt][r]);
      out[(size_t)(b * 64 + ob + r) * L_TOT + lg] =
          nh + u * (hcache[lt][r] - nh);
    }
  }
}

extern "C" void kernel_launch(void* const* d_in, const int* in_sizes, int n_in,
                              void* d_out, int out_size, void* d_ws, size_t ws_size,
                              hipStream_t stream) {
  (void)in_sizes; (void)n_in; (void)out_size; (void)ws_size;
  const float* xin = (const float*)d_in[0];
  const float* hin = (const float*)d_in[1];
  const float* Wr  = (const float*)d_in[2];
  const float* pbr = (const float*)d_in[3];
  const float* Wu  = (const float*)d_in[4];
  const float* pbu = (const float*)d_in[5];
  const float* Wh  = (const float*)d_in[6];
  const float* pbh = (const float*)d_in[7];
  float* out = (float*)d_out;

  short* whi = (short*)d_ws;
  short* wlo = whi + 192 * 128;

  hipLaunchKernelGGL(prep_weights, dim3(96), dim3(256), 0, stream,
                     Wr, Wu, Wh, whi, wlo);
  dim3 grid(L_TOT / LT, 32);
  hipLaunchKernelGGL(gru_main, grid, dim3(256), 0, stream,
                     xin, hin, whi, wlo, pbr, pbu, pbh, out);
}

// Round 4
// 715.821 us; speedup vs baseline: 1.2265x; 1.2265x over previous
//
#include <hip/hip_runtime.h>

// GRU-like fused pointwise-conv cell on MI355X (gfx950).
// B=32, C=64, H=64, L=32768. fp32 in/out; split-bf16 (hi+lo) MFMA internally.
// Round 4: fix round-3 spills (launch_bounds 256,4 -> VGPR cap 128), h from
// LDS (no global re-read). Keeps 32KB LDS alias, cvt_pk, bias-in-acc,
// shared B-frags, exp2/rcp epilogue.

typedef short s16x4 __attribute__((ext_vector_type(4)));
typedef short s16x8 __attribute__((ext_vector_type(8)));
typedef float f32x4 __attribute__((ext_vector_type(4)));
typedef unsigned u32x2 __attribute__((ext_vector_type(2)));

#define L_TOT 32768
#define LT 64          // l-points per workgroup

__device__ __forceinline__ short f2bf(float f) {
  union { float f; unsigned u; } v; v.f = f;
  unsigned r = v.u + 0x7fffu + ((v.u >> 16) & 1u);  // RNE
  return (short)(r >> 16);
}
__device__ __forceinline__ float bf2f(short s) {
  union { unsigned u; float f; } v; v.u = ((unsigned)(unsigned short)s) << 16;
  return v.f;
}
__device__ __forceinline__ unsigned cvt_pk_bf16(float a, float b) {
  unsigned r;
  asm("v_cvt_pk_bf16_f32 %0, %1, %2" : "=v"(r) : "v"(a), "v"(b));
  return r;
}
__device__ __forceinline__ float from_lo(unsigned p) {
  union { unsigned u; float f; } v; v.u = p << 16; return v.f;
}
__device__ __forceinline__ float from_hi(unsigned p) {
  union { unsigned u; float f; } v; v.u = p & 0xffff0000u; return v.f;
}
__device__ __forceinline__ float v_exp2(float x) {
  float r; asm("v_exp_f32 %0, %1" : "=v"(r) : "v"(x)); return r;
}
__device__ __forceinline__ float v_rcp(float x) {
  float r; asm("v_rcp_f32 %0, %1" : "=v"(r) : "v"(x)); return r;
}
__device__ __forceinline__ float fast_sigmoid(float x) {
  return v_rcp(1.0f + v_exp2(-1.4426950408889634f * x));
}
__device__ __forceinline__ float fast_tanh(float x) {
  return 1.0f - 2.0f * v_rcp(1.0f + v_exp2(2.8853900817779268f * x));
}

// Split W_r / W_u / W_h (each [64][128] fp32) into bf16 hi/lo arrays [192][128].
__global__ __launch_bounds__(256) void prep_weights(
    const float* __restrict__ Wr, const float* __restrict__ Wu,
    const float* __restrict__ Wh, short* __restrict__ whi,
    short* __restrict__ wlo) {
  int i = blockIdx.x * 256 + threadIdx.x;
  if (i >= 192 * 128) return;
  int r = i >> 7, c = i & 127;
  const float* src = (r < 64) ? Wr : ((r < 128) ? Wu : Wh);
  float w = src[((r & 63) << 7) | c];
  short hi = f2bf(w);
  whi[i] = hi;
  wlo[i] = f2bf(w - bf2f(hi));
}

// xt: [64 l][128 c] bf16, rows = 16 slots of 16B.
__device__ __forceinline__ int xt_idx(int l, int c) {
  int slot = ((c >> 3) ^ (l & 15) ^ (l >> 4)) & 15;
  return l * 128 + slot * 8 + (c & 7);
}
// hr: [64 l][64 c] bf16, rows = 8 slots of 16B.
__device__ __forceinline__ int hr_idx(int l, int c) {
  int slot = ((c >> 3) ^ l) & 7;
  return l * 64 + slot * 8 + (c & 7);
}

#define MFMA(a, b, c) __builtin_amdgcn_mfma_f32_16x16x32_bf16(a, b, c, 0, 0, 0)

__global__ __launch_bounds__(256, 4) void gru_main(
    const float* __restrict__ xin, const float* __restrict__ hin,
    const short* __restrict__ whi, const short* __restrict__ wlo,
    const float* __restrict__ pbr, const float* __restrict__ pbu,
    const float* __restrict__ pbh, float* __restrict__ out) {
  __shared__ __align__(16) short smem[16384];   // 32 KiB total
  short* const xt_hi = smem;                    // 16 KiB [64][128]
  short* const xt_lo = smem + 8192;             // 16 KiB
  short* const hr_hi = smem;                    // 8 KiB, aliases xt_hi (dead)
  short* const hr_lo = smem + 4096;             // 8 KiB

  const int tid  = threadIdx.x;
  const int lane = tid & 63;
  const int wv   = tid >> 6;
  const int rA   = lane & 15;
  const int hi4  = (lane >> 4) << 2;   // 0,4,8,12 -> C/D reg-row base
  const int g8   = (lane >> 4) << 3;   // k-group offset
  const int l0   = blockIdx.x * LT;
  const int b    = blockIdx.y;
  const int ob   = wv * 16 + hi4;      // first output channel of this thread

  const float* xb = xin + (size_t)b * 64 * L_TOT + l0;
  const float* hb = hin + (size_t)b * 64 * L_TOT + l0;

  // Bias folded into accumulator init.
  f32x4 bR, bU, bN;
  #pragma unroll
  for (int r = 0; r < 4; ++r) {
    bR[r] = pbr[ob + r]; bU[r] = pbu[ob + r]; bN[r] = pbh[ob + r];
  }
  f32x4 accR[4], accU[4], accN[4];
  #pragma unroll
  for (int lt = 0; lt < 4; ++lt) { accR[lt] = bR; accU[lt] = bU; accN[lt] = bN; }

  // ---- Phase 1: stage X = [input; h] transposed [l][c], bf16 hi/lo split ----
  {
    const int l = lane;
    const float* src = (wv & 2) ? hb : xb;
    const int crel = (wv & 1) * 32;              // channel within source
    #pragma unroll
    for (int it = 0; it < 8; ++it) {
      const int cs = crel + it * 4;
      const int c0 = (wv & 2) * 32 + cs;         // global c: 0..127
      const float* p = src + (size_t)cs * L_TOT + l;
      float f0 = p[0];
      float f1 = p[L_TOT];
      float f2 = p[2 * L_TOT];
      float f3 = p[3 * L_TOT];
      unsigned h01 = cvt_pk_bf16(f0, f1);
      unsigned h23 = cvt_pk_bf16(f2, f3);
      unsigned q01 = cvt_pk_bf16(f0 - from_lo(h01), f1 - from_hi(h01));
      unsigned q23 = cvt_pk_bf16(f2 - from_lo(h23), f3 - from_hi(h23));
      const int idx = xt_idx(l, c0);
      *(u32x2*)&xt_hi[idx] = u32x2{h01, h23};
      *(u32x2*)&xt_lo[idx] = u32x2{q01, q23};
    }
  }
  __syncthreads();  // sync1: X staged

  auto ldA = [&](const short* wb, int row0, int kt) -> s16x8 {
    return *(const s16x8*)&wb[(row0 + rA) * 128 + kt * 32 + g8];
  };
  auto ldBx = [&](const short* sb, int lt, int kt) -> s16x8 {
    const int l = lt * 16 + rA;
    const int c = kt * 32 + g8;
    const int slot = ((c >> 3) ^ rA ^ lt) & 15;
    return *(const s16x8*)&sb[l * 128 + slot * 8];
  };
  auto ldBh = [&](const short* sb, int lt, int kt) -> s16x8 {
    const int l = lt * 16 + rA;
    const int c = kt * 32 + g8;
    const int slot = ((c >> 3) ^ (l & 7)) & 7;
    return *(const s16x8*)&sb[l * 64 + slot * 8];
  };

  // ---- Phase 2/3 merged: R,U over K=128; N over K=0..63 shares B-frags ----
  #pragma unroll
  for (int kt = 0; kt < 4; ++kt) {
    s16x8 arh = ldA(whi, wv * 16, kt);
    s16x8 arl = ldA(wlo, wv * 16, kt);
    s16x8 auh = ldA(whi, 64 + wv * 16, kt);
    s16x8 aul = ldA(wlo, 64 + wv * 16, kt);
    if (kt < 2) {
      s16x8 anh = ldA(whi, 128 + wv * 16, kt);
      s16x8 anl = ldA(wlo, 128 + wv * 16, kt);
      #pragma unroll
      for (int lt = 0; lt < 4; ++lt) {
        s16x8 bh = ldBx(xt_hi, lt, kt);
        s16x8 bl = ldBx(xt_lo, lt, kt);
        accR[lt] = MFMA(arh, bh, accR[lt]);
        accR[lt] = MFMA(arl, bh, accR[lt]);
        accR[lt] = MFMA(arh, bl, accR[lt]);
        accU[lt] = MFMA(auh, bh, accU[lt]);
        accU[lt] = MFMA(aul, bh, accU[lt]);
        accU[lt] = MFMA(auh, bl, accU[lt]);
        accN[lt] = MFMA(anh, bh, accN[lt]);
        accN[lt] = MFMA(anl, bh, accN[lt]);
        accN[lt] = MFMA(anh, bl, accN[lt]);
      }
    } else {
      #pragma unroll
      for (int lt = 0; lt < 4; ++lt) {
        s16x8 bh = ldBx(xt_hi, lt, kt);
        s16x8 bl = ldBx(xt_lo, lt, kt);
        accR[lt] = MFMA(arh, bh, accR[lt]);
        accR[lt] = MFMA(arl, bh, accR[lt]);
        accR[lt] = MFMA(arh, bl, accR[lt]);
        accU[lt] = MFMA(auh, bh, accU[lt]);
        accU[lt] = MFMA(aul, bh, accU[lt]);
        accU[lt] = MFMA(auh, bl, accU[lt]);
      }
    }
  }

  // ---- hcache: reconstruct exact-ish h from LDS (hi+lo), b64 reads.
  // Must complete before sync2 (hr aliases xt_hi).  c = 64+ob+r, r=0..3 is
  // 4 consecutive shorts inside one 16B slot (ob%8 is 0 or 4).
  float hcache[4][4];
  #pragma unroll
  for (int lt = 0; lt < 4; ++lt) {
    const int l = lt * 16 + rA;
    const int idx = xt_idx(l, 64 + ob);
    s16x4 hv = *(const s16x4*)&xt_hi[idx];
    s16x4 lv = *(const s16x4*)&xt_lo[idx];
    #pragma unroll
    for (int r = 0; r < 4; ++r)
      hcache[lt][r] = bf2f(hv[r]) + bf2f(lv[r]);
  }

  __syncthreads();  // sync2: all waves done READING xt (hr aliases xt_hi)

  // ---- Phase 4: r = sigmoid(accR); write h*r (hi/lo split, b64 packed) ----
  #pragma unroll
  for (int lt = 0; lt < 4; ++lt) {
    const int l = lt * 16 + rA;
    float g0 = fast_sigmoid(accR[lt][0]) * hcache[lt][0];
    float g1 = fast_sigmoid(accR[lt][1]) * hcache[lt][1];
    float g2 = fast_sigmoid(accR[lt][2]) * hcache[lt][2];
    float g3 = fast_sigmoid(accR[lt][3]) * hcache[lt][3];
    unsigned h01 = cvt_pk_bf16(g0, g1);
    unsigned h23 = cvt_pk_bf16(g2, g3);
    unsigned q01 = cvt_pk_bf16(g0 - from_lo(h01), g1 - from_hi(h01));
    unsigned q23 = cvt_pk_bf16(g2 - from_lo(h23), g3 - from_hi(h23));
    const int idx = hr_idx(l, ob);
    *(u32x2*)&hr_hi[idx] = u32x2{h01, h23};
    *(u32x2*)&hr_lo[idx] = u32x2{q01, q23};
  }
  __syncthreads();  // sync3: hr ready

  // ---- Phase 5: N += W_h[:, 64:128] @ (h*r) ----
  #pragma unroll
  for (int kt = 0; kt < 2; ++kt) {
    s16x8 anh = ldA(whi, 128 + wv * 16, 2 + kt);
    s16x8 anl = ldA(wlo, 128 + wv * 16, 2 + kt);
    #pragma unroll
    for (int lt = 0; lt < 4; ++lt) {
      s16x8 bh = ldBh(hr_hi, lt, kt);
      s16x8 bl = ldBh(hr_lo, lt, kt);
      accN[lt] = MFMA(anh, bh, accN[lt]);
      accN[lt] = MFMA(anl, bh, accN[lt]);
      accN[lt] = MFMA(anh, bl, accN[lt]);
    }
  }

  // ---- Phase 6: out = (1-u)*tanh(n) + u*h ----
  #pragma unroll
  for (int lt = 0; lt < 4; ++lt) {
    const int lg = l0 + lt * 16 + rA;
    #pragma unroll
    for (int r = 0; r < 4; ++r) {
      float u  = fast_sigmoid(accU[lt][r]);
      float nh = fast_tanh(accN[lt][r]);
      out[(size_t)(b * 64 + ob + r) * L_TOT + lg] =
          nh + u * (hcache[lt][r] - nh);
    }
  }
}

extern "C" void kernel_launch(void* const* d_in, const int* in_sizes, int n_in,
                              void* d_out, int out_size, void* d_ws, size_t ws_size,
                              hipStream_t stream) {
  (void)in_sizes; (void)n_in; (void)out_size; (void)ws_size;
  const float* xin = (const float*)d_in[0];
  const float* hin = (const float*)d_in[1];
  const float* Wr  = (const float*)d_in[2];
  const float* pbr = (const float*)d_in[3];
  const float* Wu  = (const float*)d_in[4];
  const float* pbu = (const float*)d_in[5];
  const float* Wh  = (const float*)d_in[6];
  const float* pbh = (const float*)d_in[7];
  float* out = (float*)d_out;

  short* whi = (short*)d_ws;
  short* wlo = whi + 192 * 128;

  hipLaunchKernelGGL(prep_weights, dim3(96), dim3(256), 0, stream,
                     Wr, Wu, Wh, whi, wlo);
  dim3 grid(L_TOT / LT, 32);
  hipLaunchKernelGGL(gru_main, grid, dim3(256), 0, stream,
                     xin, hin, whi, wlo, pbr, pbu, pbh, out);
}